// Round 4
// baseline (308.913 us; speedup 1.0000x reference)
//
#include <hip/hip_runtime.h>
#include <hip/hip_bf16.h>

// Symmetric contraction (MACE-style), B=2048, C=256, I=9, E=10. fp32 only
// (fp32 absmax 0.5 on |out|~450 => sum|terms|/|out| ~1e4; low precision dead).
//
// Round-15: occupancy-quantum move. VGPR allocation is quantized (waves/CU
// halve at 64/128/256 -- measured r12:64->8w, r9:92->4w, r14:136->2w). r9's
// shape fills its 4-wave quantum exactly (VALUBusy 75%); instead of shaving
// slots, drop into the 64-VGPR quantum: BT=4 (acc 16), T3 streamed one
// float4 at a time (no A/B bufs), 2048 blocks -> 8 waves/SIMD co-resident.
// __launch_bounds__(256,8) pins the allocator; live set ~40 VGPR, no spill.
// ROW_FMA inner shape (e-outer, p=w*phi) is r9-identical.
// Ledger of measured lessons:
//  r2: waves/EU cap spills ONLY with big live sets (buf40+acc32); safe here.
//  r5/r12/r13: no extra 32-reg accumulator arrays (remat/AGPR shuffles).
//  r6: no global-atomic combine. r8: LDS size isn't the residency lever.
//  r9: 256-thr blocks pack CUs. r10/r14: VGPR quanta 64/128/256 are THE
//      occupancy lever; 92->136 halved waves (214us). r12: VGPR_Count is
//      the tell. r14 prep tetrahedral decode kept (rest 73->68.5us).

#define NB 2048
#define NC 256
#define NI 9
#define NE 10

#define N_TRI 165
#define N_PAIR 45
#define BT 4

// T layout (float4): T3 [165][10][256] | T2 [45][10][256] | T1 [9][10][256]
#define T3N (N_TRI * NE * NC)
#define T2N (N_PAIR * NE * NC)
#define T1N (NI * NE * NC)

// ---------------- prep: Sym (LDS) x W -> T, grid (219, 10) ----------------
__global__ __launch_bounds__(256) void sc_prep(
    const float* __restrict__ U1_s, const float* __restrict__ U2_s,
    const float* __restrict__ U3_s, const float* __restrict__ U1_v,
    const float* __restrict__ U2_v, const float* __restrict__ U3_v,
    const float* __restrict__ W1_s, const float* __restrict__ W2_s,
    const float* __restrict__ W3_s, const float* __restrict__ W1_v,
    const float* __restrict__ W2_v, const float* __restrict__ W3_v,
    float* __restrict__ ws)
{
    const int m = blockIdx.x;    // 0..218
    const int e = blockIdx.y;    // 0..9
    const int tid = threadIdx.x; // 0..255
    float4* __restrict__ T3 = (float4*)ws;
    float4* __restrict__ T2 = T3 + T3N;
    float4* __restrict__ T1 = T2 + T2N;

    __shared__ float sym[128];

    if (m < N_TRI) {
        if (tid < 113) {
            // tetrahedral decode m -> (ii<=jj<=kk), <=18 iterations
            int r = m, ii = 0;
            for (;;) {
                const int cnt = (NI - ii) * (NI - ii + 1) / 2;
                if (r < cnt) break;
                r -= cnt; ii++;
            }
            int jj = ii;
            for (;;) {
                const int cnt = NI - jj;
                if (r < cnt) break;
                r -= cnt; jj++;
            }
            const int kk = jj + r;
            int P[6][3]; int np;
            if (ii == jj && jj == kk) {
                np = 1;
                P[0][0] = ii; P[0][1] = ii; P[0][2] = ii;
            } else if (ii == jj) {
                np = 3;
                P[0][0] = ii; P[0][1] = ii; P[0][2] = kk;
                P[1][0] = ii; P[1][1] = kk; P[1][2] = ii;
                P[2][0] = kk; P[2][1] = ii; P[2][2] = ii;
            } else if (jj == kk) {
                np = 3;
                P[0][0] = ii; P[0][1] = jj; P[0][2] = jj;
                P[1][0] = jj; P[1][1] = ii; P[1][2] = jj;
                P[2][0] = jj; P[2][1] = jj; P[2][2] = ii;
            } else {
                np = 6;
                P[0][0] = ii; P[0][1] = jj; P[0][2] = kk;
                P[1][0] = ii; P[1][1] = kk; P[1][2] = jj;
                P[2][0] = jj; P[2][1] = ii; P[2][2] = kk;
                P[3][0] = jj; P[3][1] = kk; P[3][2] = ii;
                P[4][0] = kk; P[4][1] = ii; P[4][2] = jj;
                P[5][0] = kk; P[5][1] = jj; P[5][2] = ii;
            }
            float s = 0.f;
            if (tid < 23) {
                for (int p = 0; p < np; p++)
                    s += U3_s[((P[p][0] * NI + P[p][1]) * NI + P[p][2]) * 23 + tid];
            } else {
                int a = (tid - 23) / 30, t = (tid - 23) % 30;
                for (int p = 0; p < np; p++)
                    s += U3_v[(((a * NI + P[p][0]) * NI + P[p][1]) * NI + P[p][2]) * 30 + t];
            }
            sym[tid] = s;
        }
        __syncthreads();
        const int c = tid;
        float s = 0.f, v0 = 0.f, v1 = 0.f, v2 = 0.f;
        #pragma unroll
        for (int t = 0; t < 23; t++)
            s = fmaf(sym[t], W3_s[(e * 23 + t) * NC + c], s);
        #pragma unroll
        for (int t = 0; t < 30; t++) {
            float wv = W3_v[(e * 30 + t) * NC + c];
            v0 = fmaf(sym[23 + t], wv, v0);
            v1 = fmaf(sym[53 + t], wv, v1);
            v2 = fmaf(sym[83 + t], wv, v2);
        }
        T3[(m * NE + e) * NC + c] = make_float4(s, v0, v1, v2);
    } else if (m < N_TRI + N_PAIR) {
        const int mm = m - N_TRI;
        if (tid < 15) {
            // triangular decode mm -> (ii<=jj), <=9 iterations
            int r = mm, ii = 0;
            for (;;) {
                const int cnt = NI - ii;
                if (r < cnt) break;
                r -= cnt; ii++;
            }
            const int jj = ii + r;
            float s;
            if (tid < 3) {
                s = U2_s[(ii * NI + jj) * 3 + tid];
                if (ii != jj) s += U2_s[(jj * NI + ii) * 3 + tid];
            } else {
                int a = (tid - 3) / 4, t = (tid - 3) % 4;
                s = U2_v[((a * NI + ii) * NI + jj) * 4 + t];
                if (ii != jj) s += U2_v[((a * NI + jj) * NI + ii) * 4 + t];
            }
            sym[tid] = s;
        }
        __syncthreads();
        const int c = tid;
        float s = 0.f, v0 = 0.f, v1 = 0.f, v2 = 0.f;
        #pragma unroll
        for (int t = 0; t < 3; t++)
            s = fmaf(sym[t], W2_s[(e * 3 + t) * NC + c], s);
        #pragma unroll
        for (int t = 0; t < 4; t++) {
            float wv = W2_v[(e * 4 + t) * NC + c];
            v0 = fmaf(sym[3 + t],  wv, v0);
            v1 = fmaf(sym[7 + t],  wv, v1);
            v2 = fmaf(sym[11 + t], wv, v2);
        }
        T2[(mm * NE + e) * NC + c] = make_float4(s, v0, v1, v2);
    } else {
        const int i = m - N_TRI - N_PAIR;
        const int c = tid;
        float w1s = W1_s[e * NC + c], w1v = W1_v[e * NC + c];
        T1[(i * NE + e) * NC + c] = make_float4(
            U1_s[i] * w1s,
            U1_v[0 * NI + i] * w1v,
            U1_v[1 * NI + i] * w1v,
            U1_v[2 * NI + i] * w1v);
    }
}

// ---------------- main (BT=4, streamed T-rows, 8 waves/SIMD) ----------------
__device__ __forceinline__ void tri_advance(int& i, int& j, int& k) {
    k++;
    if (k == NI) { j++; if (j == NI) { i++; j = i; } k = j; }
}

// r9-identical inner shape: e-outer, p = w[e][n]*phi[n], 4 fma per (e,n).
#define ROW_STREAM(TBL, ROWIDX)                                   \
    {                                                             \
        _Pragma("unroll")                                         \
        for (int e = 0; e < NE; e++) {                            \
            const float4 t = TBL[((ROWIDX) * NE + e) * NC + c];   \
            _Pragma("unroll")                                     \
            for (int n = 0; n < BT; n++) {                        \
                const float p = w[e][n] * phi[n];                 \
                acc[n][0] = fmaf(p, t.x, acc[n][0]);              \
                acc[n][1] = fmaf(p, t.y, acc[n][1]);              \
                acc[n][2] = fmaf(p, t.z, acc[n][2]);              \
                acc[n][3] = fmaf(p, t.w, acc[n][3]);              \
            }                                                     \
        }                                                         \
    }

template <int M0, int M1, int I0, int J0, int K0>
__device__ __forceinline__ void do_triples(
    const float4* __restrict__ T3, int c, const float* __restrict__ xb,
    const float (&w)[NE][BT], float (&acc)[BT][4])
{
    int i = I0, j = J0, k = K0;
    for (int m = M0; m < M1; m++) {
        float phi[BT];
        #pragma unroll
        for (int n = 0; n < BT; n++)
            phi[n] = xb[(i * BT + n) * 64] * xb[(j * BT + n) * 64]
                   * xb[(k * BT + n) * 64];
        ROW_STREAM(T3, m)
        tri_advance(i, j, k);
    }
}

// grid 2048 x 256 threads (4 waves). One block = one (4b x 64c) tile.
// wv0: tri [0,55)  wv1: tri [55,110)  wv2: tri [110,165)  wv3: pairs+singles.
__global__ __launch_bounds__(256, 8) void sc_main(
    const float* __restrict__ x, const float* __restrict__ y,
    const float* __restrict__ ws, float* __restrict__ out)
{
    const int tid = threadIdx.x;
    const int tx  = tid & 63;
    const int wv  = __builtin_amdgcn_readfirstlane(tid >> 6);  // 0..3, uniform
    const int bid = blockIdx.x;
    const int xcd    = bid & 7;
    const int c_tile = xcd >> 1;               // XCD pair owns one c-slice of T
    const int b_tile = ((bid >> 3) << 1) | (xcd & 1);   // 0..511
    const int c0 = c_tile << 6;
    const int c  = c0 + tx;
    const int b0 = b_tile << 2;                // 4 b's per block, shared

    __shared__ float xs[NI][BT][64];    // 9.2 KB
    __shared__ float red[BT][4][64];    // 4.1 KB ping-pong combine buffer

    {
        const int n = tid >> 6, cc = tid & 63;  // 4x64 = 256 pairs exactly
        const float* xp = x + ((size_t)(b0 + n) * NC + c0 + cc) * NI;
        #pragma unroll
        for (int i = 0; i < NI; i++) xs[i][n][cc] = xp[i];
    }
    __syncthreads();
    const float* xb = &xs[0][0][tx];    // xb[(i*BT+n)*64]

    float w[NE][BT];
    #pragma unroll
    for (int n = 0; n < BT; n++)
        #pragma unroll
        for (int e = 0; e < NE; e++) w[e][n] = y[(b0 + n) * NE + e];

    float acc[BT][4];
    #pragma unroll
    for (int n = 0; n < BT; n++)
        #pragma unroll
        for (int h = 0; h < 4; h++) acc[n][h] = 0.f;

    const float4* __restrict__ T3 = (const float4*)ws;
    const float4* __restrict__ T2 = T3 + T3N;
    const float4* __restrict__ T1 = T2 + T2N;

    if (wv == 0) {
        do_triples<0, 55, 0, 0, 0>(T3, c, xb, w, acc);
    } else if (wv == 1) {
        do_triples<55, 110, 1, 2, 4>(T3, c, xb, w, acc);
    } else if (wv == 2) {
        do_triples<110, N_TRI, 3, 3, 4>(T3, c, xb, w, acc);
    } else {
        // pairs: 45 rows, streamed
        {
            int i = 0, j = 0;
            for (int m = 0; m < N_PAIR; m++) {
                float phi[BT];
                #pragma unroll
                for (int n = 0; n < BT; n++)
                    phi[n] = xb[(i * BT + n) * 64] * xb[(j * BT + n) * 64];
                ROW_STREAM(T2, m)
                j++;
                if (j == NI) { i++; j = i; }
            }
        }
        // singles: 9 rows, streamed
        for (int i = 0; i < NI; i++) {
            float phi[BT];
            #pragma unroll
            for (int n = 0; n < BT; n++) phi[n] = xb[(i * BT + n) * 64];
            ROW_STREAM(T1, i)
        }
    }

    // serial ping-pong combine: wv0 -> wv1 -> wv2 -> wv3 stores.
    if (wv == 0) {
        #pragma unroll
        for (int n = 0; n < BT; n++)
            #pragma unroll
            for (int h = 0; h < 4; h++) red[n][h][tx] = acc[n][h];
    }
    __syncthreads();
    if (wv == 1) {
        #pragma unroll
        for (int n = 0; n < BT; n++)
            #pragma unroll
            for (int h = 0; h < 4; h++) acc[n][h] += red[n][h][tx];
    }
    __syncthreads();
    if (wv == 1) {
        #pragma unroll
        for (int n = 0; n < BT; n++)
            #pragma unroll
            for (int h = 0; h < 4; h++) red[n][h][tx] = acc[n][h];
    }
    __syncthreads();
    if (wv == 2) {
        #pragma unroll
        for (int n = 0; n < BT; n++)
            #pragma unroll
            for (int h = 0; h < 4; h++) acc[n][h] += red[n][h][tx];
    }
    __syncthreads();
    if (wv == 2) {
        #pragma unroll
        for (int n = 0; n < BT; n++)
            #pragma unroll
            for (int h = 0; h < 4; h++) red[n][h][tx] = acc[n][h];
    }
    __syncthreads();
    if (wv == 3) {
        #pragma unroll
        for (int n = 0; n < BT; n++) {
            float* ob = out + (size_t)(b0 + n) * (4 * NC);
            ob[c]              = acc[n][0] + red[n][0][tx];
            ob[NC + 3 * c + 0] = acc[n][1] + red[n][1][tx];
            ob[NC + 3 * c + 1] = acc[n][2] + red[n][2][tx];
            ob[NC + 3 * c + 2] = acc[n][3] + red[n][3][tx];
        }
    }
}

extern "C" void kernel_launch(void* const* d_in, const int* in_sizes, int n_in,
                              void* d_out, int out_size, void* d_ws, size_t ws_size,
                              hipStream_t stream) {
    const float* x    = (const float*)d_in[0];
    const float* y    = (const float*)d_in[1];
    const float* U1_s = (const float*)d_in[2];
    const float* U2_s = (const float*)d_in[3];
    const float* U3_s = (const float*)d_in[4];
    const float* U1_v = (const float*)d_in[5];
    const float* U2_v = (const float*)d_in[6];
    const float* U3_v = (const float*)d_in[7];
    const float* W1_s = (const float*)d_in[8];
    const float* W2_s = (const float*)d_in[9];
    const float* W3_s = (const float*)d_in[10];
    const float* W1_v = (const float*)d_in[11];
    const float* W2_v = (const float*)d_in[12];
    const float* W3_v = (const float*)d_in[13];
    float* out = (float*)d_out;
    float* ws  = (float*)d_ws;   // 8.97 MB T table, rebuilt every call

    sc_prep<<<dim3(N_TRI + N_PAIR + NI, NE), 256, 0, stream>>>(
        U1_s, U2_s, U3_s, U1_v, U2_v, U3_v,
        W1_s, W2_s, W3_s, W1_v, W2_v, W3_v, ws);
    sc_main<<<2048, 256, 0, stream>>>(x, y, ws, out);
}

// Round 5
// 288.635 us; speedup vs baseline: 1.0703x; 1.0703x over previous
//
#include <hip/hip_runtime.h>
#include <hip/hip_bf16.h>

// Symmetric contraction (MACE-style), B=2048, C=256, I=9, E=10. fp32 only
// (fp32 absmax 0.5 on |out|~450 => sum|terms|/|out| ~1e4; low precision dead).
//
// Round-16: CONSOLIDATION. sc_main = r9 VERBATIM (measured 183us, VGPR 92,
// 4 waves/SIMD, VALUBusy 75% -- the regalloc sweet spot; r12/r13/r14/r15 all
// lost trying to beat it). sc_prep = r14 tetrahedral decode + e-loop merge:
// grid (219,10)x256 -> 219x512 (2 e's per iter, 5 iters), sym computed once
// per m instead of 10x, 219 blocks all-concurrent on 256 CUs.
// Clock model: r9 hand-count ~181K VALU-cyc/SIMD = 75us @2.4GHz @100%;
// measured 183 @75% busy => effective clock ~1.5GHz (matches m07 fp32 ubench).
// Ledger of measured lessons:
//  r2: no waves/EU cap with big live sets (spills). r5/r12/r13: no extra
//      32-reg accumulator arrays (remat / AGPR shuffles / lost prefetch).
//  r6: no global-atomic combine. r8: LDS size isn't the residency lever.
//  r9: 256-thr blocks pack CUs. r10/r14: VGPR quanta 64/128/256 are the
//      occupancy lever; crossing 128 halved waves (214us). r12: VGPR_Count
//      is the tell (92 good / 64 bad-remat). r15: BT=4 doubles T-row reads
//      (FETCH 18.6->21GB) and 8-deep TLP only buys +2-5pp VALUBusy; 217us.

#define NB 2048
#define NC 256
#define NI 9
#define NE 10

#define N_TRI 165
#define N_PAIR 45
#define BT 8

// T layout (float4): T3 [165][10][256] | T2 [45][10][256] | T1 [9][10][256]
#define T3N (N_TRI * NE * NC)
#define T2N (N_PAIR * NE * NC)
#define T1N (NI * NE * NC)

// ---------------- prep: Sym (LDS) x W -> T, grid 219 x 512 ----------------
// Block m owns one symmetric index row; e-loop inside (2 e's per iteration).
__global__ __launch_bounds__(512) void sc_prep(
    const float* __restrict__ U1_s, const float* __restrict__ U2_s,
    const float* __restrict__ U3_s, const float* __restrict__ U1_v,
    const float* __restrict__ U2_v, const float* __restrict__ U3_v,
    const float* __restrict__ W1_s, const float* __restrict__ W2_s,
    const float* __restrict__ W3_s, const float* __restrict__ W1_v,
    const float* __restrict__ W2_v, const float* __restrict__ W3_v,
    float* __restrict__ ws)
{
    const int m = blockIdx.x;    // 0..218
    const int tid = threadIdx.x; // 0..511
    const int c  = tid & 255;
    const int eh = tid >> 8;     // 0..1
    float4* __restrict__ T3 = (float4*)ws;
    float4* __restrict__ T2 = T3 + T3N;
    float4* __restrict__ T1 = T2 + T2N;

    __shared__ float sym[128];

    if (m < N_TRI) {
        if (tid < 113) {
            // tetrahedral decode m -> (ii<=jj<=kk), <=18 iterations
            int r = m, ii = 0;
            for (;;) {
                const int cnt = (NI - ii) * (NI - ii + 1) / 2;
                if (r < cnt) break;
                r -= cnt; ii++;
            }
            int jj = ii;
            for (;;) {
                const int cnt = NI - jj;
                if (r < cnt) break;
                r -= cnt; jj++;
            }
            const int kk = jj + r;
            int P[6][3]; int np;
            if (ii == jj && jj == kk) {
                np = 1;
                P[0][0] = ii; P[0][1] = ii; P[0][2] = ii;
            } else if (ii == jj) {
                np = 3;
                P[0][0] = ii; P[0][1] = ii; P[0][2] = kk;
                P[1][0] = ii; P[1][1] = kk; P[1][2] = ii;
                P[2][0] = kk; P[2][1] = ii; P[2][2] = ii;
            } else if (jj == kk) {
                np = 3;
                P[0][0] = ii; P[0][1] = jj; P[0][2] = jj;
                P[1][0] = jj; P[1][1] = ii; P[1][2] = jj;
                P[2][0] = jj; P[2][1] = jj; P[2][2] = ii;
            } else {
                np = 6;
                P[0][0] = ii; P[0][1] = jj; P[0][2] = kk;
                P[1][0] = ii; P[1][1] = kk; P[1][2] = jj;
                P[2][0] = jj; P[2][1] = ii; P[2][2] = kk;
                P[3][0] = jj; P[3][1] = kk; P[3][2] = ii;
                P[4][0] = kk; P[4][1] = ii; P[4][2] = jj;
                P[5][0] = kk; P[5][1] = jj; P[5][2] = ii;
            }
            float s = 0.f;
            if (tid < 23) {
                for (int p = 0; p < np; p++)
                    s += U3_s[((P[p][0] * NI + P[p][1]) * NI + P[p][2]) * 23 + tid];
            } else {
                int a = (tid - 23) / 30, t = (tid - 23) % 30;
                for (int p = 0; p < np; p++)
                    s += U3_v[(((a * NI + P[p][0]) * NI + P[p][1]) * NI + P[p][2]) * 30 + t];
            }
            sym[tid] = s;
        }
        __syncthreads();
        #pragma unroll
        for (int it = 0; it < 5; it++) {
            const int e = it * 2 + eh;
            float s = 0.f, v0 = 0.f, v1 = 0.f, v2 = 0.f;
            #pragma unroll
            for (int t = 0; t < 23; t++)
                s = fmaf(sym[t], W3_s[(e * 23 + t) * NC + c], s);
            #pragma unroll
            for (int t = 0; t < 30; t++) {
                float wv = W3_v[(e * 30 + t) * NC + c];
                v0 = fmaf(sym[23 + t], wv, v0);
                v1 = fmaf(sym[53 + t], wv, v1);
                v2 = fmaf(sym[83 + t], wv, v2);
            }
            T3[(m * NE + e) * NC + c] = make_float4(s, v0, v1, v2);
        }
    } else if (m < N_TRI + N_PAIR) {
        const int mm = m - N_TRI;
        if (tid < 15) {
            // triangular decode mm -> (ii<=jj), <=9 iterations
            int r = mm, ii = 0;
            for (;;) {
                const int cnt = NI - ii;
                if (r < cnt) break;
                r -= cnt; ii++;
            }
            const int jj = ii + r;
            float s;
            if (tid < 3) {
                s = U2_s[(ii * NI + jj) * 3 + tid];
                if (ii != jj) s += U2_s[(jj * NI + ii) * 3 + tid];
            } else {
                int a = (tid - 3) / 4, t = (tid - 3) % 4;
                s = U2_v[((a * NI + ii) * NI + jj) * 4 + t];
                if (ii != jj) s += U2_v[((a * NI + jj) * NI + ii) * 4 + t];
            }
            sym[tid] = s;
        }
        __syncthreads();
        #pragma unroll
        for (int it = 0; it < 5; it++) {
            const int e = it * 2 + eh;
            float s = 0.f, v0 = 0.f, v1 = 0.f, v2 = 0.f;
            #pragma unroll
            for (int t = 0; t < 3; t++)
                s = fmaf(sym[t], W2_s[(e * 3 + t) * NC + c], s);
            #pragma unroll
            for (int t = 0; t < 4; t++) {
                float wv = W2_v[(e * 4 + t) * NC + c];
                v0 = fmaf(sym[3 + t],  wv, v0);
                v1 = fmaf(sym[7 + t],  wv, v1);
                v2 = fmaf(sym[11 + t], wv, v2);
            }
            T2[(mm * NE + e) * NC + c] = make_float4(s, v0, v1, v2);
        }
    } else {
        const int i = m - N_TRI - N_PAIR;
        #pragma unroll
        for (int it = 0; it < 5; it++) {
            const int e = it * 2 + eh;
            float w1s = W1_s[e * NC + c], w1v = W1_v[e * NC + c];
            T1[(i * NE + e) * NC + c] = make_float4(
                U1_s[i] * w1s,
                U1_v[0 * NI + i] * w1v,
                U1_v[1 * NI + i] * w1v,
                U1_v[2 * NI + i] * w1v);
        }
    }
}

// ---------------- main (r9 verbatim) ----------------
__device__ __forceinline__ void tri_advance(int& i, int& j, int& k) {
    k++;
    if (k == NI) { j++; if (j == NI) { i++; j = i; } k = j; }
}

#define ROW_FMA(BUF)                                              \
    {                                                             \
        _Pragma("unroll")                                         \
        for (int e = 0; e < NE; e++) {                            \
            const float4 t = BUF[e];                              \
            _Pragma("unroll")                                     \
            for (int n = 0; n < BT; n++) {                        \
                const float p = w[e][n] * phi[n];                 \
                acc[n][0] = fmaf(p, t.x, acc[n][0]);              \
                acc[n][1] = fmaf(p, t.y, acc[n][1]);              \
                acc[n][2] = fmaf(p, t.z, acc[n][2]);              \
                acc[n][3] = fmaf(p, t.w, acc[n][3]);              \
            }                                                     \
        }                                                         \
    }

template <int M0, int M1, int I0, int J0, int K0>
__device__ __forceinline__ void do_triples(
    const float4* __restrict__ T3, int c, const float* __restrict__ xb,
    const float (&w)[NE][BT], float (&acc)[BT][4])
{
    float4 bufA[NE], bufB[NE];
    #pragma unroll
    for (int e = 0; e < NE; e++) bufA[e] = T3[(M0 * NE + e) * NC + c];
    int i = I0, j = J0, k = K0;
    for (int m = M0; m + 1 < M1; m += 2) {
        #pragma unroll
        for (int e = 0; e < NE; e++) bufB[e] = T3[((m + 1) * NE + e) * NC + c];
        {
            float phi[BT];
            #pragma unroll
            for (int n = 0; n < BT; n++)
                phi[n] = xb[(i * BT + n) * 64] * xb[(j * BT + n) * 64]
                       * xb[(k * BT + n) * 64];
            ROW_FMA(bufA)
        }
        tri_advance(i, j, k);
        const int mp = (m + 2 < M1) ? m + 2 : M1 - 1;
        #pragma unroll
        for (int e = 0; e < NE; e++) bufA[e] = T3[(mp * NE + e) * NC + c];
        {
            float phi[BT];
            #pragma unroll
            for (int n = 0; n < BT; n++)
                phi[n] = xb[(i * BT + n) * 64] * xb[(j * BT + n) * 64]
                       * xb[(k * BT + n) * 64];
            ROW_FMA(bufB)
        }
        tri_advance(i, j, k);
    }
    if ((M1 - M0) & 1) {
        float phi[BT];
        #pragma unroll
        for (int n = 0; n < BT; n++)
            phi[n] = xb[(i * BT + n) * 64] * xb[(j * BT + n) * 64]
                   * xb[(k * BT + n) * 64];
        ROW_FMA(bufA)
    }
}

// grid 1024 x 256 threads (4 waves). One block = one (8b x 64c) tile.
// wv0: tri [0,55)  wv1: tri [55,110)  wv2: tri [110,165)  wv3: pairs+singles.
__global__ __launch_bounds__(256) void sc_main(
    const float* __restrict__ x, const float* __restrict__ y,
    const float* __restrict__ ws, float* __restrict__ out)
{
    const int tid = threadIdx.x;
    const int tx  = tid & 63;
    const int wv  = __builtin_amdgcn_readfirstlane(tid >> 6);  // 0..3, uniform
    const int bid = blockIdx.x;
    const int xcd    = bid & 7;
    const int c_tile = xcd >> 1;               // XCD pair owns one c-slice of T
    const int b_tile = ((bid >> 3) << 1) | (xcd & 1);   // 0..255
    const int c0 = c_tile << 6;
    const int c  = c0 + tx;
    const int b0 = b_tile << 3;                // 8 b's per block, shared

    __shared__ float xs[NI][BT][64];    // 18.4 KB, shared by all 4 waves
    __shared__ float red[BT][4][64];    //  8.2 KB ping-pong combine buffer

    #pragma unroll
    for (int p = 0; p < 2; p++) {
        const int pair = tid + p * 256;
        const int n = pair >> 6, cc = pair & 63;
        const float* xp = x + ((size_t)(b0 + n) * NC + c0 + cc) * NI;
        #pragma unroll
        for (int i = 0; i < NI; i++) xs[i][n][cc] = xp[i];
    }
    __syncthreads();
    const float* xb = &xs[0][0][tx];    // xb[(i*BT+n)*64]

    float w[NE][BT];
    #pragma unroll
    for (int n = 0; n < BT; n++)
        #pragma unroll
        for (int e = 0; e < NE; e++) w[e][n] = y[(b0 + n) * NE + e];

    float acc[BT][4];
    #pragma unroll
    for (int n = 0; n < BT; n++)
        #pragma unroll
        for (int h = 0; h < 4; h++) acc[n][h] = 0.f;

    const float4* __restrict__ T3 = (const float4*)ws;
    const float4* __restrict__ T2 = T3 + T3N;
    const float4* __restrict__ T1 = T2 + T2N;

    if (wv == 0) {
        do_triples<0, 55, 0, 0, 0>(T3, c, xb, w, acc);
    } else if (wv == 1) {
        do_triples<55, 110, 1, 2, 4>(T3, c, xb, w, acc);
    } else if (wv == 2) {
        do_triples<110, N_TRI, 3, 3, 4>(T3, c, xb, w, acc);
    } else {
        // pairs: 45 rows, unroll-2 A/B
        {
            float4 bufA[NE], bufB[NE];
            #pragma unroll
            for (int e = 0; e < NE; e++) bufA[e] = T2[e * NC + c];
            int i = 0, j = 0;
            for (int m = 0; m + 1 < N_PAIR; m += 2) {
                #pragma unroll
                for (int e = 0; e < NE; e++) bufB[e] = T2[((m + 1) * NE + e) * NC + c];
                {
                    float phi[BT];
                    #pragma unroll
                    for (int n = 0; n < BT; n++)
                        phi[n] = xb[(i * BT + n) * 64] * xb[(j * BT + n) * 64];
                    ROW_FMA(bufA)
                }
                j++; if (j == NI) { i++; j = i; }
                const int mp = (m + 2 < N_PAIR) ? m + 2 : N_PAIR - 1;
                #pragma unroll
                for (int e = 0; e < NE; e++) bufA[e] = T2[(mp * NE + e) * NC + c];
                {
                    float phi[BT];
                    #pragma unroll
                    for (int n = 0; n < BT; n++)
                        phi[n] = xb[(i * BT + n) * 64] * xb[(j * BT + n) * 64];
                    ROW_FMA(bufB)
                }
                j++; if (j == NI) { i++; j = i; }
            }
            {   // tail row 44 in bufA
                float phi[BT];
                #pragma unroll
                for (int n = 0; n < BT; n++)
                    phi[n] = xb[(i * BT + n) * 64] * xb[(j * BT + n) * 64];
                ROW_FMA(bufA)
            }
        }
        // singles
        for (int i = 0; i < NI; i++) {
            float4 tc[NE];
            #pragma unroll
            for (int e = 0; e < NE; e++) tc[e] = T1[(i * NE + e) * NC + c];
            float phi[BT];
            #pragma unroll
            for (int n = 0; n < BT; n++) phi[n] = xb[(i * BT + n) * 64];
            ROW_FMA(tc)
        }
    }

    // serial ping-pong combine: wv0 -> wv1 -> wv2 -> wv3 stores.
    if (wv == 0) {
        #pragma unroll
        for (int n = 0; n < BT; n++)
            #pragma unroll
            for (int h = 0; h < 4; h++) red[n][h][tx] = acc[n][h];
    }
    __syncthreads();
    if (wv == 1) {
        #pragma unroll
        for (int n = 0; n < BT; n++)
            #pragma unroll
            for (int h = 0; h < 4; h++) acc[n][h] += red[n][h][tx];
    }
    __syncthreads();
    if (wv == 1) {
        #pragma unroll
        for (int n = 0; n < BT; n++)
            #pragma unroll
            for (int h = 0; h < 4; h++) red[n][h][tx] = acc[n][h];
    }
    __syncthreads();
    if (wv == 2) {
        #pragma unroll
        for (int n = 0; n < BT; n++)
            #pragma unroll
            for (int h = 0; h < 4; h++) acc[n][h] += red[n][h][tx];
    }
    __syncthreads();
    if (wv == 2) {
        #pragma unroll
        for (int n = 0; n < BT; n++)
            #pragma unroll
            for (int h = 0; h < 4; h++) red[n][h][tx] = acc[n][h];
    }
    __syncthreads();
    if (wv == 3) {
        #pragma unroll
        for (int n = 0; n < BT; n++) {
            float* ob = out + (size_t)(b0 + n) * (4 * NC);
            ob[c]              = acc[n][0] + red[n][0][tx];
            ob[NC + 3 * c + 0] = acc[n][1] + red[n][1][tx];
            ob[NC + 3 * c + 1] = acc[n][2] + red[n][2][tx];
            ob[NC + 3 * c + 2] = acc[n][3] + red[n][3][tx];
        }
    }
}

extern "C" void kernel_launch(void* const* d_in, const int* in_sizes, int n_in,
                              void* d_out, int out_size, void* d_ws, size_t ws_size,
                              hipStream_t stream) {
    const float* x    = (const float*)d_in[0];
    const float* y    = (const float*)d_in[1];
    const float* U1_s = (const float*)d_in[2];
    const float* U2_s = (const float*)d_in[3];
    const float* U3_s = (const float*)d_in[4];
    const float* U1_v = (const float*)d_in[5];
    const float* U2_v = (const float*)d_in[6];
    const float* U3_v = (const float*)d_in[7];
    const float* W1_s = (const float*)d_in[8];
    const float* W2_s = (const float*)d_in[9];
    const float* W3_s = (const float*)d_in[10];
    const float* W1_v = (const float*)d_in[11];
    const float* W2_v = (const float*)d_in[12];
    const float* W3_v = (const float*)d_in[13];
    float* out = (float*)d_out;
    float* ws  = (float*)d_ws;   // 8.97 MB T table, rebuilt every call

    sc_prep<<<N_TRI + N_PAIR + NI, 512, 0, stream>>>(
        U1_s, U2_s, U3_s, U1_v, U2_v, U3_v,
        W1_s, W2_s, W3_s, W1_v, W2_v, W3_v, ws);
    sc_main<<<1024, 256, 0, stream>>>(x, y, ws, out);
}

// Round 6
// 266.989 us; speedup vs baseline: 1.1570x; 1.0811x over previous
//
#include <hip/hip_runtime.h>
#include <hip/hip_bf16.h>

// Symmetric contraction (MACE-style), B=2048, C=256, I=9, E=10. fp32 only
// (fp32 absmax 0.5 on |out|~450 => sum|terms|/|out| ~1e4; low precision dead).
//
// Round-17: bank the two best MEASURED halves together.
//  sc_main = r9 VERBATIM (183-185us reproduced 3x: VGPR 92, 4 waves/SIMD,
//            VALUBusy ~75%).
//  sc_prep = r14 VERBATIM: grid (219,10)x256 + tetrahedral decode
//            (rest = total-main: r11 scan 81us, r14 tetra 68.8us,
//             r16 e-merged 103.9us -- e-merge kills prep TLP, re-learned r4).
// Clock model: r9 hand-count ~181K VALU-cyc/SIMD = 75us @2.4GHz @100%;
// measured 184 @75% busy => effective clock ~1.5GHz (matches m07 fp32 ubench)
// -> main is VALU-throughput-bound at its regalloc sweet spot.
// Ledger of measured lessons:
//  r2: no waves/EU cap with big live sets (spills). r4/r16: prep wants the
//      (219,10) grid -- e-loop-in-block serializes W-load chains (~+35us).
//  r5/r12/r13: no extra 32-reg accumulator arrays (remat/AGPR shuffles).
//  r6: no global-atomic combine. r8: LDS size isn't the residency lever.
//  r9: 256-thr blocks pack CUs. r10/r14: VGPR quanta 64/128/256 are the
//      occupancy lever; crossing 128 halves waves (214us). r12: VGPR_Count
//      is the tell (92 good / 64 bad-remat). r15: BT=4 doubles T-row reads
//      and 8-deep TLP only buys +2-5pp VALUBusy (217us).

#define NB 2048
#define NC 256
#define NI 9
#define NE 10

#define N_TRI 165
#define N_PAIR 45
#define BT 8

// T layout (float4): T3 [165][10][256] | T2 [45][10][256] | T1 [9][10][256]
#define T3N (N_TRI * NE * NC)
#define T2N (N_PAIR * NE * NC)
#define T1N (NI * NE * NC)

// ---------------- prep: Sym (LDS) x W -> T, grid (219, 10) ----------------
__global__ __launch_bounds__(256) void sc_prep(
    const float* __restrict__ U1_s, const float* __restrict__ U2_s,
    const float* __restrict__ U3_s, const float* __restrict__ U1_v,
    const float* __restrict__ U2_v, const float* __restrict__ U3_v,
    const float* __restrict__ W1_s, const float* __restrict__ W2_s,
    const float* __restrict__ W3_s, const float* __restrict__ W1_v,
    const float* __restrict__ W2_v, const float* __restrict__ W3_v,
    float* __restrict__ ws)
{
    const int m = blockIdx.x;    // 0..218
    const int e = blockIdx.y;    // 0..9
    const int tid = threadIdx.x; // 0..255
    float4* __restrict__ T3 = (float4*)ws;
    float4* __restrict__ T2 = T3 + T3N;
    float4* __restrict__ T1 = T2 + T2N;

    __shared__ float sym[128];

    if (m < N_TRI) {
        if (tid < 113) {
            // tetrahedral decode m -> (ii<=jj<=kk), <=18 iterations
            int r = m, ii = 0;
            for (;;) {
                const int cnt = (NI - ii) * (NI - ii + 1) / 2;
                if (r < cnt) break;
                r -= cnt; ii++;
            }
            int jj = ii;
            for (;;) {
                const int cnt = NI - jj;
                if (r < cnt) break;
                r -= cnt; jj++;
            }
            const int kk = jj + r;
            int P[6][3]; int np;
            if (ii == jj && jj == kk) {
                np = 1;
                P[0][0] = ii; P[0][1] = ii; P[0][2] = ii;
            } else if (ii == jj) {
                np = 3;
                P[0][0] = ii; P[0][1] = ii; P[0][2] = kk;
                P[1][0] = ii; P[1][1] = kk; P[1][2] = ii;
                P[2][0] = kk; P[2][1] = ii; P[2][2] = ii;
            } else if (jj == kk) {
                np = 3;
                P[0][0] = ii; P[0][1] = jj; P[0][2] = jj;
                P[1][0] = jj; P[1][1] = ii; P[1][2] = jj;
                P[2][0] = jj; P[2][1] = jj; P[2][2] = ii;
            } else {
                np = 6;
                P[0][0] = ii; P[0][1] = jj; P[0][2] = kk;
                P[1][0] = ii; P[1][1] = kk; P[1][2] = jj;
                P[2][0] = jj; P[2][1] = ii; P[2][2] = kk;
                P[3][0] = jj; P[3][1] = kk; P[3][2] = ii;
                P[4][0] = kk; P[4][1] = ii; P[4][2] = jj;
                P[5][0] = kk; P[5][1] = jj; P[5][2] = ii;
            }
            float s = 0.f;
            if (tid < 23) {
                for (int p = 0; p < np; p++)
                    s += U3_s[((P[p][0] * NI + P[p][1]) * NI + P[p][2]) * 23 + tid];
            } else {
                int a = (tid - 23) / 30, t = (tid - 23) % 30;
                for (int p = 0; p < np; p++)
                    s += U3_v[(((a * NI + P[p][0]) * NI + P[p][1]) * NI + P[p][2]) * 30 + t];
            }
            sym[tid] = s;
        }
        __syncthreads();
        const int c = tid;
        float s = 0.f, v0 = 0.f, v1 = 0.f, v2 = 0.f;
        #pragma unroll
        for (int t = 0; t < 23; t++)
            s = fmaf(sym[t], W3_s[(e * 23 + t) * NC + c], s);
        #pragma unroll
        for (int t = 0; t < 30; t++) {
            float wv = W3_v[(e * 30 + t) * NC + c];
            v0 = fmaf(sym[23 + t], wv, v0);
            v1 = fmaf(sym[53 + t], wv, v1);
            v2 = fmaf(sym[83 + t], wv, v2);
        }
        T3[(m * NE + e) * NC + c] = make_float4(s, v0, v1, v2);
    } else if (m < N_TRI + N_PAIR) {
        const int mm = m - N_TRI;
        if (tid < 15) {
            // triangular decode mm -> (ii<=jj), <=9 iterations
            int r = mm, ii = 0;
            for (;;) {
                const int cnt = NI - ii;
                if (r < cnt) break;
                r -= cnt; ii++;
            }
            const int jj = ii + r;
            float s;
            if (tid < 3) {
                s = U2_s[(ii * NI + jj) * 3 + tid];
                if (ii != jj) s += U2_s[(jj * NI + ii) * 3 + tid];
            } else {
                int a = (tid - 3) / 4, t = (tid - 3) % 4;
                s = U2_v[((a * NI + ii) * NI + jj) * 4 + t];
                if (ii != jj) s += U2_v[((a * NI + jj) * NI + ii) * 4 + t];
            }
            sym[tid] = s;
        }
        __syncthreads();
        const int c = tid;
        float s = 0.f, v0 = 0.f, v1 = 0.f, v2 = 0.f;
        #pragma unroll
        for (int t = 0; t < 3; t++)
            s = fmaf(sym[t], W2_s[(e * 3 + t) * NC + c], s);
        #pragma unroll
        for (int t = 0; t < 4; t++) {
            float wv = W2_v[(e * 4 + t) * NC + c];
            v0 = fmaf(sym[3 + t],  wv, v0);
            v1 = fmaf(sym[7 + t],  wv, v1);
            v2 = fmaf(sym[11 + t], wv, v2);
        }
        T2[(mm * NE + e) * NC + c] = make_float4(s, v0, v1, v2);
    } else {
        const int i = m - N_TRI - N_PAIR;
        const int c = tid;
        float w1s = W1_s[e * NC + c], w1v = W1_v[e * NC + c];
        T1[(i * NE + e) * NC + c] = make_float4(
            U1_s[i] * w1s,
            U1_v[0 * NI + i] * w1v,
            U1_v[1 * NI + i] * w1v,
            U1_v[2 * NI + i] * w1v);
    }
}

// ---------------- main (r9 verbatim) ----------------
__device__ __forceinline__ void tri_advance(int& i, int& j, int& k) {
    k++;
    if (k == NI) { j++; if (j == NI) { i++; j = i; } k = j; }
}

#define ROW_FMA(BUF)                                              \
    {                                                             \
        _Pragma("unroll")                                         \
        for (int e = 0; e < NE; e++) {                            \
            const float4 t = BUF[e];                              \
            _Pragma("unroll")                                     \
            for (int n = 0; n < BT; n++) {                        \
                const float p = w[e][n] * phi[n];                 \
                acc[n][0] = fmaf(p, t.x, acc[n][0]);              \
                acc[n][1] = fmaf(p, t.y, acc[n][1]);              \
                acc[n][2] = fmaf(p, t.z, acc[n][2]);              \
                acc[n][3] = fmaf(p, t.w, acc[n][3]);              \
            }                                                     \
        }                                                         \
    }

template <int M0, int M1, int I0, int J0, int K0>
__device__ __forceinline__ void do_triples(
    const float4* __restrict__ T3, int c, const float* __restrict__ xb,
    const float (&w)[NE][BT], float (&acc)[BT][4])
{
    float4 bufA[NE], bufB[NE];
    #pragma unroll
    for (int e = 0; e < NE; e++) bufA[e] = T3[(M0 * NE + e) * NC + c];
    int i = I0, j = J0, k = K0;
    for (int m = M0; m + 1 < M1; m += 2) {
        #pragma unroll
        for (int e = 0; e < NE; e++) bufB[e] = T3[((m + 1) * NE + e) * NC + c];
        {
            float phi[BT];
            #pragma unroll
            for (int n = 0; n < BT; n++)
                phi[n] = xb[(i * BT + n) * 64] * xb[(j * BT + n) * 64]
                       * xb[(k * BT + n) * 64];
            ROW_FMA(bufA)
        }
        tri_advance(i, j, k);
        const int mp = (m + 2 < M1) ? m + 2 : M1 - 1;
        #pragma unroll
        for (int e = 0; e < NE; e++) bufA[e] = T3[(mp * NE + e) * NC + c];
        {
            float phi[BT];
            #pragma unroll
            for (int n = 0; n < BT; n++)
                phi[n] = xb[(i * BT + n) * 64] * xb[(j * BT + n) * 64]
                       * xb[(k * BT + n) * 64];
            ROW_FMA(bufB)
        }
        tri_advance(i, j, k);
    }
    if ((M1 - M0) & 1) {
        float phi[BT];
        #pragma unroll
        for (int n = 0; n < BT; n++)
            phi[n] = xb[(i * BT + n) * 64] * xb[(j * BT + n) * 64]
                   * xb[(k * BT + n) * 64];
        ROW_FMA(bufA)
    }
}

// grid 1024 x 256 threads (4 waves). One block = one (8b x 64c) tile.
// wv0: tri [0,55)  wv1: tri [55,110)  wv2: tri [110,165)  wv3: pairs+singles.
__global__ __launch_bounds__(256) void sc_main(
    const float* __restrict__ x, const float* __restrict__ y,
    const float* __restrict__ ws, float* __restrict__ out)
{
    const int tid = threadIdx.x;
    const int tx  = tid & 63;
    const int wv  = __builtin_amdgcn_readfirstlane(tid >> 6);  // 0..3, uniform
    const int bid = blockIdx.x;
    const int xcd    = bid & 7;
    const int c_tile = xcd >> 1;               // XCD pair owns one c-slice of T
    const int b_tile = ((bid >> 3) << 1) | (xcd & 1);   // 0..255
    const int c0 = c_tile << 6;
    const int c  = c0 + tx;
    const int b0 = b_tile << 3;                // 8 b's per block, shared

    __shared__ float xs[NI][BT][64];    // 18.4 KB, shared by all 4 waves
    __shared__ float red[BT][4][64];    //  8.2 KB ping-pong combine buffer

    #pragma unroll
    for (int p = 0; p < 2; p++) {
        const int pair = tid + p * 256;
        const int n = pair >> 6, cc = pair & 63;
        const float* xp = x + ((size_t)(b0 + n) * NC + c0 + cc) * NI;
        #pragma unroll
        for (int i = 0; i < NI; i++) xs[i][n][cc] = xp[i];
    }
    __syncthreads();
    const float* xb = &xs[0][0][tx];    // xb[(i*BT+n)*64]

    float w[NE][BT];
    #pragma unroll
    for (int n = 0; n < BT; n++)
        #pragma unroll
        for (int e = 0; e < NE; e++) w[e][n] = y[(b0 + n) * NE + e];

    float acc[BT][4];
    #pragma unroll
    for (int n = 0; n < BT; n++)
        #pragma unroll
        for (int h = 0; h < 4; h++) acc[n][h] = 0.f;

    const float4* __restrict__ T3 = (const float4*)ws;
    const float4* __restrict__ T2 = T3 + T3N;
    const float4* __restrict__ T1 = T2 + T2N;

    if (wv == 0) {
        do_triples<0, 55, 0, 0, 0>(T3, c, xb, w, acc);
    } else if (wv == 1) {
        do_triples<55, 110, 1, 2, 4>(T3, c, xb, w, acc);
    } else if (wv == 2) {
        do_triples<110, N_TRI, 3, 3, 4>(T3, c, xb, w, acc);
    } else {
        // pairs: 45 rows, unroll-2 A/B
        {
            float4 bufA[NE], bufB[NE];
            #pragma unroll
            for (int e = 0; e < NE; e++) bufA[e] = T2[e * NC + c];
            int i = 0, j = 0;
            for (int m = 0; m + 1 < N_PAIR; m += 2) {
                #pragma unroll
                for (int e = 0; e < NE; e++) bufB[e] = T2[((m + 1) * NE + e) * NC + c];
                {
                    float phi[BT];
                    #pragma unroll
                    for (int n = 0; n < BT; n++)
                        phi[n] = xb[(i * BT + n) * 64] * xb[(j * BT + n) * 64];
                    ROW_FMA(bufA)
                }
                j++; if (j == NI) { i++; j = i; }
                const int mp = (m + 2 < N_PAIR) ? m + 2 : N_PAIR - 1;
                #pragma unroll
                for (int e = 0; e < NE; e++) bufA[e] = T2[(mp * NE + e) * NC + c];
                {
                    float phi[BT];
                    #pragma unroll
                    for (int n = 0; n < BT; n++)
                        phi[n] = xb[(i * BT + n) * 64] * xb[(j * BT + n) * 64];
                    ROW_FMA(bufB)
                }
                j++; if (j == NI) { i++; j = i; }
            }
            {   // tail row 44 in bufA
                float phi[BT];
                #pragma unroll
                for (int n = 0; n < BT; n++)
                    phi[n] = xb[(i * BT + n) * 64] * xb[(j * BT + n) * 64];
                ROW_FMA(bufA)
            }
        }
        // singles
        for (int i = 0; i < NI; i++) {
            float4 tc[NE];
            #pragma unroll
            for (int e = 0; e < NE; e++) tc[e] = T1[(i * NE + e) * NC + c];
            float phi[BT];
            #pragma unroll
            for (int n = 0; n < BT; n++) phi[n] = xb[(i * BT + n) * 64];
            ROW_FMA(tc)
        }
    }

    // serial ping-pong combine: wv0 -> wv1 -> wv2 -> wv3 stores.
    if (wv == 0) {
        #pragma unroll
        for (int n = 0; n < BT; n++)
            #pragma unroll
            for (int h = 0; h < 4; h++) red[n][h][tx] = acc[n][h];
    }
    __syncthreads();
    if (wv == 1) {
        #pragma unroll
        for (int n = 0; n < BT; n++)
            #pragma unroll
            for (int h = 0; h < 4; h++) acc[n][h] += red[n][h][tx];
    }
    __syncthreads();
    if (wv == 1) {
        #pragma unroll
        for (int n = 0; n < BT; n++)
            #pragma unroll
            for (int h = 0; h < 4; h++) red[n][h][tx] = acc[n][h];
    }
    __syncthreads();
    if (wv == 2) {
        #pragma unroll
        for (int n = 0; n < BT; n++)
            #pragma unroll
            for (int h = 0; h < 4; h++) acc[n][h] += red[n][h][tx];
    }
    __syncthreads();
    if (wv == 2) {
        #pragma unroll
        for (int n = 0; n < BT; n++)
            #pragma unroll
            for (int h = 0; h < 4; h++) red[n][h][tx] = acc[n][h];
    }
    __syncthreads();
    if (wv == 3) {
        #pragma unroll
        for (int n = 0; n < BT; n++) {
            float* ob = out + (size_t)(b0 + n) * (4 * NC);
            ob[c]              = acc[n][0] + red[n][0][tx];
            ob[NC + 3 * c + 0] = acc[n][1] + red[n][1][tx];
            ob[NC + 3 * c + 1] = acc[n][2] + red[n][2][tx];
            ob[NC + 3 * c + 2] = acc[n][3] + red[n][3][tx];
        }
    }
}

extern "C" void kernel_launch(void* const* d_in, const int* in_sizes, int n_in,
                              void* d_out, int out_size, void* d_ws, size_t ws_size,
                              hipStream_t stream) {
    const float* x    = (const float*)d_in[0];
    const float* y    = (const float*)d_in[1];
    const float* U1_s = (const float*)d_in[2];
    const float* U2_s = (const float*)d_in[3];
    const float* U3_s = (const float*)d_in[4];
    const float* U1_v = (const float*)d_in[5];
    const float* U2_v = (const float*)d_in[6];
    const float* U3_v = (const float*)d_in[7];
    const float* W1_s = (const float*)d_in[8];
    const float* W2_s = (const float*)d_in[9];
    const float* W3_s = (const float*)d_in[10];
    const float* W1_v = (const float*)d_in[11];
    const float* W2_v = (const float*)d_in[12];
    const float* W3_v = (const float*)d_in[13];
    float* out = (float*)d_out;
    float* ws  = (float*)d_ws;   // 8.97 MB T table, rebuilt every call

    sc_prep<<<dim3(N_TRI + N_PAIR + NI, NE), 256, 0, stream>>>(
        U1_s, U2_s, U3_s, U1_v, U2_v, U3_v,
        W1_s, W2_s, W3_s, W1_v, W2_v, W3_v, ws);
    sc_main<<<1024, 256, 0, stream>>>(x, y, ws, out);
}

// Round 7
// 265.607 us; speedup vs baseline: 1.1630x; 1.0052x over previous
//
#include <hip/hip_runtime.h>
#include <hip/hip_bf16.h>

// Symmetric contraction (MACE-style), B=2048, C=256, I=9, E=10. fp32 only
// (fp32 absmax 0.5 on |out|~450 => sum|terms|/|out| ~1e4; low precision dead).
//
// Round-18: branch-free table-driven main. The r9 body's tri_advance branch
// blocked cross-row scheduling: phi's 24 ds_reads issued right before use
// (~120cyc lgkm stall/row/wave = the 24% VALU idle). Replace the (i,j,k)
// walk with constexpr packed tables (TRI[165]/PAIR[45], uniform index ->
// s_load from constant cache); 2-row body is now straight-line, phiA+phiB
// reads issue at top and hide under ROW_FMA(A). No new persistent arrays
// (transient phiB[8] only; the r12/r13 failure family added LIVE arrays).
// Cycle model: 55 rows x ~880cyc x 4 waves/SIMD = 194K cyc => 129us @100%
// busy @1.5GHz effective; r9 measured 184 @76% -> ~55us stall to reclaim.
// Ledger of measured lessons:
//  r2: no waves/EU cap with big live sets (spills). r4/r16: prep wants the
//      (219,10) grid (e-loop serializes W-chains). r5/r12/r13: no extra
//      32-reg live accumulator arrays (remat/AGPR shuffles). r6: no
//      global-atomic combine. r8: LDS size isn't the residency lever.
//  r9: 256-thr blocks pack CUs; main 183-186 reproduced 5x (VGPR 92).
//  r10/r14: VGPR quanta 64/128/256 are the occupancy lever; >128 halves
//      waves (214us). r12: VGPR_Count is the tell. r15: BT=4 doubles T-row
//      reads, 8-deep TLP only +2-5pp busy. r14/r17: prep decode style is
//      noise; rest ~70-85us mostly harness overhead.

#define NB 2048
#define NC 256
#define NI 9
#define NE 10

#define N_TRI 165
#define N_PAIR 45
#define BT 8

// T layout (float4): T3 [165][10][256] | T2 [45][10][256] | T1 [9][10][256]
#define T3N (N_TRI * NE * NC)
#define T2N (N_PAIR * NE * NC)
#define T1N (NI * NE * NC)

// ---- compile-time index tables (uniform index -> constant-cache s_load) ----
struct Tri165 { int v[N_TRI]; };
static constexpr Tri165 make_tri165() {
    Tri165 t{}; int m = 0;
    for (int i = 0; i < NI; i++)
        for (int j = i; j < NI; j++)
            for (int k = j; k < NI; k++)
                t.v[m++] = (i << 8) | (j << 4) | k;
    return t;
}
__device__ constexpr Tri165 TRI = make_tri165();

struct Pair45 { int v[N_PAIR]; };
static constexpr Pair45 make_pair45() {
    Pair45 t{}; int m = 0;
    for (int i = 0; i < NI; i++)
        for (int j = i; j < NI; j++)
            t.v[m++] = (i << 4) | j;
    return t;
}
__device__ constexpr Pair45 PAIR = make_pair45();

// ---------------- prep: Sym (LDS) x W -> T, grid (219, 10) ----------------
__global__ __launch_bounds__(256) void sc_prep(
    const float* __restrict__ U1_s, const float* __restrict__ U2_s,
    const float* __restrict__ U3_s, const float* __restrict__ U1_v,
    const float* __restrict__ U2_v, const float* __restrict__ U3_v,
    const float* __restrict__ W1_s, const float* __restrict__ W2_s,
    const float* __restrict__ W3_s, const float* __restrict__ W1_v,
    const float* __restrict__ W2_v, const float* __restrict__ W3_v,
    float* __restrict__ ws)
{
    const int m = blockIdx.x;    // 0..218
    const int e = blockIdx.y;    // 0..9
    const int tid = threadIdx.x; // 0..255
    float4* __restrict__ T3 = (float4*)ws;
    float4* __restrict__ T2 = T3 + T3N;
    float4* __restrict__ T1 = T2 + T2N;

    __shared__ float sym[128];

    if (m < N_TRI) {
        if (tid < 113) {
            const int v = TRI.v[m];
            const int ii = v >> 8, jj = (v >> 4) & 15, kk = v & 15;
            int P[6][3]; int np;
            if (ii == jj && jj == kk) {
                np = 1;
                P[0][0] = ii; P[0][1] = ii; P[0][2] = ii;
            } else if (ii == jj) {
                np = 3;
                P[0][0] = ii; P[0][1] = ii; P[0][2] = kk;
                P[1][0] = ii; P[1][1] = kk; P[1][2] = ii;
                P[2][0] = kk; P[2][1] = ii; P[2][2] = ii;
            } else if (jj == kk) {
                np = 3;
                P[0][0] = ii; P[0][1] = jj; P[0][2] = jj;
                P[1][0] = jj; P[1][1] = ii; P[1][2] = jj;
                P[2][0] = jj; P[2][1] = jj; P[2][2] = ii;
            } else {
                np = 6;
                P[0][0] = ii; P[0][1] = jj; P[0][2] = kk;
                P[1][0] = ii; P[1][1] = kk; P[1][2] = jj;
                P[2][0] = jj; P[2][1] = ii; P[2][2] = kk;
                P[3][0] = jj; P[3][1] = kk; P[3][2] = ii;
                P[4][0] = kk; P[4][1] = ii; P[4][2] = jj;
                P[5][0] = kk; P[5][1] = jj; P[5][2] = ii;
            }
            float s = 0.f;
            if (tid < 23) {
                for (int p = 0; p < np; p++)
                    s += U3_s[((P[p][0] * NI + P[p][1]) * NI + P[p][2]) * 23 + tid];
            } else {
                int a = (tid - 23) / 30, t = (tid - 23) % 30;
                for (int p = 0; p < np; p++)
                    s += U3_v[(((a * NI + P[p][0]) * NI + P[p][1]) * NI + P[p][2]) * 30 + t];
            }
            sym[tid] = s;
        }
        __syncthreads();
        const int c = tid;
        float s = 0.f, v0 = 0.f, v1 = 0.f, v2 = 0.f;
        #pragma unroll
        for (int t = 0; t < 23; t++)
            s = fmaf(sym[t], W3_s[(e * 23 + t) * NC + c], s);
        #pragma unroll
        for (int t = 0; t < 30; t++) {
            float wv = W3_v[(e * 30 + t) * NC + c];
            v0 = fmaf(sym[23 + t], wv, v0);
            v1 = fmaf(sym[53 + t], wv, v1);
            v2 = fmaf(sym[83 + t], wv, v2);
        }
        T3[(m * NE + e) * NC + c] = make_float4(s, v0, v1, v2);
    } else if (m < N_TRI + N_PAIR) {
        const int mm = m - N_TRI;
        if (tid < 15) {
            const int v = PAIR.v[mm];
            const int ii = v >> 4, jj = v & 15;
            float s;
            if (tid < 3) {
                s = U2_s[(ii * NI + jj) * 3 + tid];
                if (ii != jj) s += U2_s[(jj * NI + ii) * 3 + tid];
            } else {
                int a = (tid - 3) / 4, t = (tid - 3) % 4;
                s = U2_v[((a * NI + ii) * NI + jj) * 4 + t];
                if (ii != jj) s += U2_v[((a * NI + jj) * NI + ii) * 4 + t];
            }
            sym[tid] = s;
        }
        __syncthreads();
        const int c = tid;
        float s = 0.f, v0 = 0.f, v1 = 0.f, v2 = 0.f;
        #pragma unroll
        for (int t = 0; t < 3; t++)
            s = fmaf(sym[t], W2_s[(e * 3 + t) * NC + c], s);
        #pragma unroll
        for (int t = 0; t < 4; t++) {
            float wv = W2_v[(e * 4 + t) * NC + c];
            v0 = fmaf(sym[3 + t],  wv, v0);
            v1 = fmaf(sym[7 + t],  wv, v1);
            v2 = fmaf(sym[11 + t], wv, v2);
        }
        T2[(mm * NE + e) * NC + c] = make_float4(s, v0, v1, v2);
    } else {
        const int i = m - N_TRI - N_PAIR;
        const int c = tid;
        float w1s = W1_s[e * NC + c], w1v = W1_v[e * NC + c];
        T1[(i * NE + e) * NC + c] = make_float4(
            U1_s[i] * w1s,
            U1_v[0 * NI + i] * w1v,
            U1_v[1 * NI + i] * w1v,
            U1_v[2 * NI + i] * w1v);
    }
}

// ---------------- main (branch-free table-driven rows) ----------------
#define ROW_FMA(BUF, PHI)                                         \
    {                                                             \
        _Pragma("unroll")                                         \
        for (int e = 0; e < NE; e++) {                            \
            const float4 t = BUF[e];                              \
            _Pragma("unroll")                                     \
            for (int n = 0; n < BT; n++) {                        \
                const float p = w[e][n] * PHI[n];                 \
                acc[n][0] = fmaf(p, t.x, acc[n][0]);              \
                acc[n][1] = fmaf(p, t.y, acc[n][1]);              \
                acc[n][2] = fmaf(p, t.z, acc[n][2]);              \
                acc[n][3] = fmaf(p, t.w, acc[n][3]);              \
            }                                                     \
        }                                                         \
    }

// phi = xi*xj*xk with (i,j,k) unpacked from packed table entry (uniform).
#define PHI3(PHI, V)                                              \
    {                                                             \
        const int i_ = (V) >> 8, j_ = ((V) >> 4) & 15, k_ = (V) & 15; \
        _Pragma("unroll")                                         \
        for (int n = 0; n < BT; n++)                              \
            PHI[n] = xb[(i_ * BT + n) * 64] * xb[(j_ * BT + n) * 64] \
                   * xb[(k_ * BT + n) * 64];                      \
    }

#define PHI2(PHI, V)                                              \
    {                                                             \
        const int i_ = (V) >> 4, j_ = (V) & 15;                   \
        _Pragma("unroll")                                         \
        for (int n = 0; n < BT; n++)                              \
            PHI[n] = xb[(i_ * BT + n) * 64] * xb[(j_ * BT + n) * 64]; \
    }

template <int M0, int M1>
__device__ __forceinline__ void do_triples(
    const float4* __restrict__ T3, int c, const float* __restrict__ xb,
    const float (&w)[NE][BT], float (&acc)[BT][4])
{
    float4 bufA[NE], bufB[NE];
    #pragma unroll
    for (int e = 0; e < NE; e++) bufA[e] = T3[(M0 * NE + e) * NC + c];
    for (int m = M0; m + 1 < M1; m += 2) {
        #pragma unroll
        for (int e = 0; e < NE; e++) bufB[e] = T3[((m + 1) * NE + e) * NC + c];
        float phiA[BT], phiB[BT];
        PHI3(phiA, TRI.v[m])
        PHI3(phiB, TRI.v[m + 1])
        ROW_FMA(bufA, phiA)
        const int mp = (m + 2 < M1) ? m + 2 : M1 - 1;
        #pragma unroll
        for (int e = 0; e < NE; e++) bufA[e] = T3[(mp * NE + e) * NC + c];
        ROW_FMA(bufB, phiB)
    }
    if ((M1 - M0) & 1) {
        float phiA[BT];
        PHI3(phiA, TRI.v[M1 - 1])
        ROW_FMA(bufA, phiA)
    }
}

// grid 1024 x 256 threads (4 waves). One block = one (8b x 64c) tile.
// wv0: tri [0,55)  wv1: tri [55,110)  wv2: tri [110,165)  wv3: pairs+singles.
__global__ __launch_bounds__(256) void sc_main(
    const float* __restrict__ x, const float* __restrict__ y,
    const float* __restrict__ ws, float* __restrict__ out)
{
    const int tid = threadIdx.x;
    const int tx  = tid & 63;
    const int wv  = __builtin_amdgcn_readfirstlane(tid >> 6);  // 0..3, uniform
    const int bid = blockIdx.x;
    const int xcd    = bid & 7;
    const int c_tile = xcd >> 1;               // XCD pair owns one c-slice of T
    const int b_tile = ((bid >> 3) << 1) | (xcd & 1);   // 0..255
    const int c0 = c_tile << 6;
    const int c  = c0 + tx;
    const int b0 = b_tile << 3;                // 8 b's per block, shared

    __shared__ float xs[NI][BT][64];    // 18.4 KB, shared by all 4 waves
    __shared__ float red[BT][4][64];    //  8.2 KB ping-pong combine buffer

    #pragma unroll
    for (int p = 0; p < 2; p++) {
        const int pair = tid + p * 256;
        const int n = pair >> 6, cc = pair & 63;
        const float* xp = x + ((size_t)(b0 + n) * NC + c0 + cc) * NI;
        #pragma unroll
        for (int i = 0; i < NI; i++) xs[i][n][cc] = xp[i];
    }
    __syncthreads();
    const float* xb = &xs[0][0][tx];    // xb[(i*BT+n)*64]

    float w[NE][BT];
    #pragma unroll
    for (int n = 0; n < BT; n++)
        #pragma unroll
        for (int e = 0; e < NE; e++) w[e][n] = y[(b0 + n) * NE + e];

    float acc[BT][4];
    #pragma unroll
    for (int n = 0; n < BT; n++)
        #pragma unroll
        for (int h = 0; h < 4; h++) acc[n][h] = 0.f;

    const float4* __restrict__ T3 = (const float4*)ws;
    const float4* __restrict__ T2 = T3 + T3N;
    const float4* __restrict__ T1 = T2 + T2N;

    if (wv == 0) {
        do_triples<0, 55>(T3, c, xb, w, acc);
    } else if (wv == 1) {
        do_triples<55, 110>(T3, c, xb, w, acc);
    } else if (wv == 2) {
        do_triples<110, N_TRI>(T3, c, xb, w, acc);
    } else {
        // pairs: 45 rows, unroll-2 A/B, table-driven
        {
            float4 bufA[NE], bufB[NE];
            #pragma unroll
            for (int e = 0; e < NE; e++) bufA[e] = T2[e * NC + c];
            for (int m = 0; m + 1 < N_PAIR; m += 2) {
                #pragma unroll
                for (int e = 0; e < NE; e++) bufB[e] = T2[((m + 1) * NE + e) * NC + c];
                float phiA[BT], phiB[BT];
                PHI2(phiA, PAIR.v[m])
                PHI2(phiB, PAIR.v[m + 1])
                ROW_FMA(bufA, phiA)
                const int mp = (m + 2 < N_PAIR) ? m + 2 : N_PAIR - 1;
                #pragma unroll
                for (int e = 0; e < NE; e++) bufA[e] = T2[(mp * NE + e) * NC + c];
                ROW_FMA(bufB, phiB)
            }
            {   // tail row 44 in bufA
                float phiA[BT];
                PHI2(phiA, PAIR.v[N_PAIR - 1])
                ROW_FMA(bufA, phiA)
            }
        }
        // singles
        for (int i = 0; i < NI; i++) {
            float4 tc[NE];
            #pragma unroll
            for (int e = 0; e < NE; e++) tc[e] = T1[(i * NE + e) * NC + c];
            float phi[BT];
            #pragma unroll
            for (int n = 0; n < BT; n++) phi[n] = xb[(i * BT + n) * 64];
            ROW_FMA(tc, phi)
        }
    }

    // serial ping-pong combine: wv0 -> wv1 -> wv2 -> wv3 stores.
    if (wv == 0) {
        #pragma unroll
        for (int n = 0; n < BT; n++)
            #pragma unroll
            for (int h = 0; h < 4; h++) red[n][h][tx] = acc[n][h];
    }
    __syncthreads();
    if (wv == 1) {
        #pragma unroll
        for (int n = 0; n < BT; n++)
            #pragma unroll
            for (int h = 0; h < 4; h++) acc[n][h] += red[n][h][tx];
    }
    __syncthreads();
    if (wv == 1) {
        #pragma unroll
        for (int n = 0; n < BT; n++)
            #pragma unroll
            for (int h = 0; h < 4; h++) red[n][h][tx] = acc[n][h];
    }
    __syncthreads();
    if (wv == 2) {
        #pragma unroll
        for (int n = 0; n < BT; n++)
            #pragma unroll
            for (int h = 0; h < 4; h++) acc[n][h] += red[n][h][tx];
    }
    __syncthreads();
    if (wv == 2) {
        #pragma unroll
        for (int n = 0; n < BT; n++)
            #pragma unroll
            for (int h = 0; h < 4; h++) red[n][h][tx] = acc[n][h];
    }
    __syncthreads();
    if (wv == 3) {
        #pragma unroll
        for (int n = 0; n < BT; n++) {
            float* ob = out + (size_t)(b0 + n) * (4 * NC);
            ob[c]              = acc[n][0] + red[n][0][tx];
            ob[NC + 3 * c + 0] = acc[n][1] + red[n][1][tx];
            ob[NC + 3 * c + 1] = acc[n][2] + red[n][2][tx];
            ob[NC + 3 * c + 2] = acc[n][3] + red[n][3][tx];
        }
    }
}

extern "C" void kernel_launch(void* const* d_in, const int* in_sizes, int n_in,
                              void* d_out, int out_size, void* d_ws, size_t ws_size,
                              hipStream_t stream) {
    const float* x    = (const float*)d_in[0];
    const float* y    = (const float*)d_in[1];
    const float* U1_s = (const float*)d_in[2];
    const float* U2_s = (const float*)d_in[3];
    const float* U3_s = (const float*)d_in[4];
    const float* U1_v = (const float*)d_in[5];
    const float* U2_v = (const float*)d_in[6];
    const float* U3_v = (const float*)d_in[7];
    const float* W1_s = (const float*)d_in[8];
    const float* W2_s = (const float*)d_in[9];
    const float* W3_s = (const float*)d_in[10];
    const float* W1_v = (const float*)d_in[11];
    const float* W2_v = (const float*)d_in[12];
    const float* W3_v = (const float*)d_in[13];
    float* out = (float*)d_out;
    float* ws  = (float*)d_ws;   // 8.97 MB T table, rebuilt every call

    sc_prep<<<dim3(N_TRI + N_PAIR + NI, NE), 256, 0, stream>>>(
        U1_s, U2_s, U3_s, U1_v, U2_v, U3_v,
        W1_s, W2_s, W3_s, W1_v, W2_v, W3_v, ws);
    sc_main<<<1024, 256, 0, stream>>>(x, y, ws, out);
}